// Round 7
// baseline (4285.581 us; speedup 1.0000x reference)
//
#include <hip/hip_runtime.h>
#include <stdint.h>

// GRU encoder: B=64 T=512 U=E=1024 V=32000, gates z|r|h, reset_after=True.
// Round-13 structure:
//   Phase 0: init_h  — split hidden -> bf16 hi/lo planes, zero 8 group counters.
//   Phase 1: gemm_xp — unchanged proven kernel: xp int16 @2^17.
//   Phase 2: gru_scan — persistent, 256 WGs x 512 thr (1 WG/CU, NO residency
//     gamble — r12's 2-WG/CU + VGPR-128 pin spilled to scratch, spills are
//     vmem ops that corrupted the counted WAITVs -> NaN).
//     r11 diagnosis stands: latency/skew-bound; the exposed cost is the
//     barrier chain (drain->arrival->detect->release) right after the same
//     step's arrivals. r13: TWO independent recurrence chains per WG
//     (batch rows independent): WG-set s owns groups 2s (rows 16s..+8) and
//     2s+1 (rows +8..+16); 8 barriers of 64 WGs. Step = phase A then B;
//     chain A's barrier(t) is polled AFTER phase B(t-1) (~2500cy later),
//     chain B's after phase A(t): barrier RT + skew hides under the other
//     chain's data phase. Chains share the register-resident B-frags.
//     Data path/protocol verbatim r9-proven: bf16 hi/lo h exchange (no
//     unpack on the ladder), counted vmcnt (counts re-verified for epi/
//     non-epi x both phases), lane-major part, tid0 atomic, w0 sleep-poll.
// ws: xp 201.33MB | h hi/lo planes 2x2x128KB | counters 2KB = 201.85MB.

#define B_SZ   64
#define T_LEN  512
#define U_DIM  1024
#define E_DIM  1024
#define G3     3072
#define BU     (B_SZ * U_DIM)
#define XP_SCALE 131072.0f
#define XP_INV   (1.0f / 131072.0f)
#define LDT    40   // gemm LDS row stride (ushorts): 80B, 16B-aligned
#define NWG    256
#define GRPWG  64   // WGs per batch-group barrier

typedef unsigned short ushort_t;
typedef __attribute__((ext_vector_type(8))) short bf16x8;
typedef __attribute__((ext_vector_type(4))) float f32x4;

__device__ __forceinline__ ushort_t f2bf(float f) {
  unsigned u = __builtin_bit_cast(unsigned, f);
  u += 0x7fffu + ((u >> 16) & 1u);          // RNE
  return (ushort_t)(u >> 16);
}
__device__ __forceinline__ float bf2f(ushort_t h) {
  return __builtin_bit_cast(float, (unsigned)h << 16);
}

// ---- coherent (MALL-point) memory ops: bypass L1+L2 via sc0 sc1 ----
__device__ __forceinline__ bf16x8 ldg_cohere_b128(const void* p) {
  bf16x8 r;
  asm volatile("global_load_dwordx4 %0, %1, off sc0 sc1"
               : "=v"(r) : "v"(p) : "memory");
  return r;
}
__device__ __forceinline__ void stg_cohere_u16(ushort_t* p, unsigned v) {
  asm volatile("global_store_short %0, %1, off sc0 sc1"
               :: "v"(p), "v"(v) : "memory");
}
__device__ __forceinline__ unsigned ldg_cohere_u32(const unsigned* p) {
  unsigned r;
  asm volatile("global_load_dword %0, %1, off sc0 sc1\n\ts_waitcnt vmcnt(0)"
               : "=v"(r) : "v"(p) : "memory");
  return r;
}
// ---- ordinary cached ops, but as ordered volatile asm (vmcnt counting) ----
__device__ __forceinline__ int ldg_sshort(const short* p) {
  int r;
  asm volatile("global_load_sshort %0, %1, off"
               : "=v"(r) : "v"(p) : "memory");
  return r;
}
__device__ __forceinline__ int ldg_s32(const int* p) {
  int r;
  asm volatile("global_load_dword %0, %1, off"
               : "=v"(r) : "v"(p) : "memory");
  return r;
}
__device__ __forceinline__ void stg_u32(float* p, float v) {
  asm volatile("global_store_dword %0, %1, off"
               :: "v"(p), "v"(v) : "memory");
}
#define WAITV(n) do { asm volatile("s_waitcnt vmcnt(" #n ")" ::: "memory"); \
                      __builtin_amdgcn_sched_barrier(0); } while (0)

// ---------------- Phase 1: gathered GEMM, 128x128 tile, BK=32, 4 waves,
// split-bf16, 41KB pure-static LDS (unchanged proven kernel).
__global__ __launch_bounds__(256) void gemm_xp(
    const float* __restrict__ emb,    // [V][1024] f32 (gathered rows)
    const float* __restrict__ Wx,     // [1024][3072] f32
    const int* __restrict__ x,        // [B*T] (m = b*T+t)
    const float* __restrict__ b_i,    // [3072]
    short* __restrict__ xp)           // [T][B][3072] int16 (x 2^17)
{
  __shared__ ushort_t aH[128 * LDT];
  __shared__ ushort_t aL[128 * LDT];
  __shared__ ushort_t bH[128 * LDT];
  __shared__ ushort_t bL[128 * LDT];
  const int tid = threadIdx.x, lane = tid & 63, w = tid >> 6;
  const int bx = blockIdx.x;
  const int nIdx = bx % 24, mIdx = bx / 24;
  const int m0 = mIdx * 128, n0 = nIdx * 128;

  const int aRow0 = tid >> 2, aRow1 = (tid + 256) >> 2, aKoct = tid & 3;
  const size_t aBase0 = (size_t)x[m0 + aRow0] * E_DIM + (size_t)aKoct * 8;
  const size_t aBase1 = (size_t)x[m0 + aRow1] * E_DIM + (size_t)aKoct * 8;
  const int bN = tid & 127, bKoct0 = tid >> 7;

  const int wr = (w >> 1) * 64, wc = (w & 1) * 64;
  f32x4 acc[4][4];
#pragma unroll
  for (int i = 0; i < 4; i++)
#pragma unroll
    for (int j = 0; j < 4; j++) acc[i][j] = (f32x4){0.f, 0.f, 0.f, 0.f};

  for (int k0 = 0; k0 < E_DIM; k0 += 32) {
    __syncthreads();
#pragma unroll
    for (int pp = 0; pp < 2; ++pp) {
      const float* src = emb + (pp ? aBase1 : aBase0) + k0;
      int row = pp ? aRow1 : aRow0;
      float4 v0 = *(const float4*)(src);
      float4 v1 = *(const float4*)(src + 4);
      float vv[8] = {v0.x, v0.y, v0.z, v0.w, v1.x, v1.y, v1.z, v1.w};
      bf16x8 oh, ol;
#pragma unroll
      for (int j = 0; j < 8; ++j) {
        ushort_t hi = f2bf(vv[j]);
        oh[j] = (short)hi;
        ol[j] = (short)f2bf(vv[j] - bf2f(hi));
      }
      int off = row * LDT + aKoct * 8;
      *(bf16x8*)&aH[off] = oh;
      *(bf16x8*)&aL[off] = ol;
    }
#pragma unroll
    for (int kk = 0; kk < 2; ++kk) {
      int koct = bKoct0 + 2 * kk;
      float vv[8];
#pragma unroll
      for (int e = 0; e < 8; ++e)
        vv[e] = Wx[(size_t)(k0 + koct * 8 + e) * G3 + n0 + bN];
      bf16x8 oh, ol;
#pragma unroll
      for (int j = 0; j < 8; ++j) {
        ushort_t hi = f2bf(vv[j]);
        oh[j] = (short)hi;
        ol[j] = (short)f2bf(vv[j] - bf2f(hi));
      }
      int off = bN * LDT + koct * 8;
      *(bf16x8*)&bH[off] = oh;
      *(bf16x8*)&bL[off] = ol;
    }
    __syncthreads();
    bf16x8 afH[4], afL[4], bfH[4], bfL[4];
#pragma unroll
    for (int mi = 0; mi < 4; mi++) {
      int off = (wr + mi * 16 + (lane & 15)) * LDT + (lane >> 4) * 8;
      afH[mi] = *(const bf16x8*)&aH[off];
      afL[mi] = *(const bf16x8*)&aL[off];
    }
#pragma unroll
    for (int ni = 0; ni < 4; ni++) {
      int off = (wc + ni * 16 + (lane & 15)) * LDT + (lane >> 4) * 8;
      bfH[ni] = *(const bf16x8*)&bH[off];
      bfL[ni] = *(const bf16x8*)&bL[off];
    }
#pragma unroll
    for (int mi = 0; mi < 4; mi++)
#pragma unroll
      for (int ni = 0; ni < 4; ni++) {
        acc[mi][ni] = __builtin_amdgcn_mfma_f32_16x16x32_bf16(afH[mi], bfH[ni], acc[mi][ni], 0, 0, 0);
        acc[mi][ni] = __builtin_amdgcn_mfma_f32_16x16x32_bf16(afH[mi], bfL[ni], acc[mi][ni], 0, 0, 0);
        acc[mi][ni] = __builtin_amdgcn_mfma_f32_16x16x32_bf16(afL[mi], bfH[ni], acc[mi][ni], 0, 0, 0);
      }
  }
#pragma unroll
  for (int ni = 0; ni < 4; ni++) {
    int col = n0 + wc + ni * 16 + (lane & 15);
    float bias = b_i[col];
#pragma unroll
    for (int mi = 0; mi < 4; mi++) {
      int rbase = m0 + wr + mi * 16 + (lane >> 4) * 4;
#pragma unroll
      for (int i = 0; i < 4; i++) {
        int m = rbase + i;
        int b = m >> 9, t = m & 511;
        float v = acc[mi][ni][i] + bias;
        int q = __float2int_rn(v * XP_SCALE);
        q = q > 32767 ? 32767 : (q < -32768 ? -32768 : q);
        xp[(size_t)(t * 64 + b) * G3 + col] = (short)q;
      }
    }
  }
}

// ---------------- Phase 0: split hidden -> bf16 hi/lo planes (buffer 0),
// zero the 8 group-barrier counters (256B apart = 512 u32).
__global__ __launch_bounds__(256) void init_h(
    const float* __restrict__ hidden,
    ushort_t* __restrict__ hHI, ushort_t* __restrict__ hLO,
    unsigned* __restrict__ cnt)
{
  const int i = blockIdx.x * 256 + threadIdx.x;
  if (blockIdx.x < 2) cnt[blockIdx.x * 256 + threadIdx.x] = 0u;
  if (i < BU) {
    const float v = hidden[i];
    const ushort_t hi = f2bf(v);
    hHI[i] = hi;
    hLO[i] = f2bf(v - bf2f(hi));
  }
}

// ---------------- Phase 2: persistent GRU scan, paired-chain pipeline.
// WG(bx): uj = bx&63 (u-tile of 16), sgrp = bx>>6 (0..3). Chains c=0,1 =
// batch-groups 2*sgrp+c (rows 16*sgrp + 8c .. +8). 8 barriers x 64 WGs.
// Wave w (0..7) owns K-segment [128w,128w+128). Verified MFMA layouts:
// A row=lane&15 k=(lane>>4)*8+j; B col=lane&15 same k; C row=(lane>>4)*4+i
// col=lane&15. A rows: 8 real rows duplicated via (c16&7) (dup lanes load
// the same address -> coalesced; C rows 8-15 unused). Per phase: poll
// (hidden under other chain's phase) -> 8 hi/lo A-loads -> counted ladder
// -> part -> reduce/epi -> drain -> arrival. Both chains share B-frags.
__global__ __launch_bounds__(512) void gru_scan(
    const float* __restrict__ hidden,  // [64][1024] f32 (hp init)
    const float* __restrict__ Wh,      // [1024][3072] f32
    const float* __restrict__ b_r,     // [3072]
    const short* __restrict__ xp,      // [T][64][3072] int16
    const int* __restrict__ x,         // [64][512]
    ushort_t* __restrict__ hHI,        // [2][64][1024] bf16 hi planes
    ushort_t* __restrict__ hLO,        // [2][64][1024] bf16 lo planes
    unsigned* __restrict__ cnt,        // 8 group counters, 64 uints apart
    float* __restrict__ out)           // [64][512][1024] f32 + [64][1024] state
{
  __shared__ float part[8][3][64][4];   // [kseg][gate][lane][elem] 24KB
  const int tid  = threadIdx.x;
  const int lane = tid & 63;
  const int w    = tid >> 6;            // wave id = K-segment
  const int bx   = (int)blockIdx.x;
  const int uj   = bx & 63, sgrp = bx >> 6;
  const int u0   = uj * 16, b0 = sgrp * 16;
  const int c16  = lane & 15;           // fragment row/col-within-tile
  const int kg   = lane >> 4;           // k-group (x8)

  // ---- Wh fragments resident in registers (built once, cached loads) ----
  bf16x8 BH[4][3], BL[4][3];
#pragma unroll
  for (int ks = 0; ks < 4; ++ks)
#pragma unroll
    for (int g = 0; g < 3; ++g) {
      bf16x8 bh, bl;
#pragma unroll
      for (int j = 0; j < 8; ++j) {
        int k = w * 128 + ks * 32 + kg * 8 + j;
        float v = Wh[(size_t)k * G3 + g * 1024 + u0 + c16];
        ushort_t hi = f2bf(v);
        bh[j] = (short)hi;
        bl[j] = (short)f2bf(v - bf2f(hi));
      }
      BH[ks][g] = bh;
      BL[ks][g] = bl;
    }

  // ---- epilogue ownership: waves 0-1 (tid<128): per phase, one (b,u)
  // per thread: row ebl (0..7) of the phase's 8-row group, col eul.
  const bool epi = (tid < 128);
  const int ebl = tid >> 4, eul = tid & 15;
  const int eu = u0 + eul;
  float brz = 0.f, brr = 0.f, brh = 0.f;
  float hp[2] = {0.f, 0.f};
  if (epi) {
    brz = b_r[eu]; brr = b_r[1024 + eu]; brh = b_r[2048 + eu];
    hp[0] = hidden[(size_t)(b0 + ebl) * U_DIM + eu];
    hp[1] = hidden[(size_t)(b0 + 8 + ebl) * U_DIM + eu];
  }

  // drain everything before entering the counted-vmcnt regime
  asm volatile("s_waitcnt vmcnt(0) lgkmcnt(0)" ::: "memory");

  // prologue: prefetch xq for t=0, both chains (epi: 8 in-flight loads;
  // all WAITV counts below verified for epi/non-epi x both phases).
  int xq[2][3], xtok[2];
  xq[0][0] = xq[0][1] = xq[0][2] = xq[1][0] = xq[1][1] = xq[1][2] = 0;
  xtok[0] = xtok[1] = 0;
  if (epi) {
#pragma unroll
    for (int c = 0; c < 2; ++c) {
      const int eb = b0 + c * 8 + ebl;
      xq[c][0] = ldg_sshort(xp + (size_t)eb * G3 + eu);
      xq[c][1] = ldg_sshort(xp + (size_t)eb * G3 + 1024 + eu);
      xq[c][2] = ldg_sshort(xp + (size_t)eb * G3 + 2048 + eu);
      xtok[c]  = ldg_s32(x + eb * T_LEN + 0);
    }
  }

  unsigned spins = 0;            // global spin budget: deadlock bails visibly
  for (int t = 0; t < T_LEN; ++t) {
    const ushort_t* __restrict__ rH = hHI + (size_t)(t & 1) * BU;
    const ushort_t* __restrict__ rL = hLO + (size_t)(t & 1) * BU;
    ushort_t* __restrict__ wrH = hHI + (size_t)((t + 1) & 1) * BU;
    ushort_t* __restrict__ wrL = hLO + (size_t)((t + 1) & 1) * BU;
    const unsigned tgt = (unsigned)t * GRPWG;   // step t needs step t-1 done

#pragma unroll
    for (int c = 0; c < 2; ++c) {               // phase A (c=0), phase B (c=1)
      const int b0c = b0 + c * 8;
      unsigned* mycnt = cnt + (2 * sgrp + c) * 64;

      // ---- barrier wait (hidden: arrivals happened one phase ago) ----
      if (w == 0) {
        while (spins < (1u << 22)) {
          if (ldg_cohere_u32(mycnt) >= tgt) break;
          __builtin_amdgcn_s_sleep(2);
          ++spins;
        }
      }
      __syncthreads();   // release: h(t) of this chain is MALL-visible

      // A rows = this chain's 8 h-rows, duplicated across 16 frag rows
      const ushort_t* pH = rH + (size_t)(b0c + (c16 & 7)) * U_DIM + w * 128 + kg * 8;
      const ushort_t* pL = rL + (size_t)(b0c + (c16 & 7)) * U_DIM + w * 128 + kg * 8;

      f32x4 acc[3];
#pragma unroll
      for (int g = 0; g < 3; ++g) acc[g] = (f32x4){0.f, 0.f, 0.f, 0.f};

      // 8 loads upfront; FIFO waits (any older xq retire first, harmless):
      //   WAITV(6)->H0,L0 ready | (4)->H1,L1 | (2)->H2,L2 | (0)->all.
      bf16x8 AH0, AL0, AH1, AL1, AH2, AL2, AH3, AL3;
      AH0 = ldg_cohere_b128(pH + 0 * 32);  AL0 = ldg_cohere_b128(pL + 0 * 32);
      AH1 = ldg_cohere_b128(pH + 1 * 32);  AL1 = ldg_cohere_b128(pL + 1 * 32);
      AH2 = ldg_cohere_b128(pH + 2 * 32);  AL2 = ldg_cohere_b128(pL + 2 * 32);
      AH3 = ldg_cohere_b128(pH + 3 * 32);  AL3 = ldg_cohere_b128(pL + 3 * 32);

#define COMP(AH_, AL_, ks_) \
      _Pragma("unroll") \
      for (int g = 0; g < 3; ++g) { \
        acc[g] = __builtin_amdgcn_mfma_f32_16x16x32_bf16(AH_, BH[ks_][g], acc[g], 0, 0, 0); \
        acc[g] = __builtin_amdgcn_mfma_f32_16x16x32_bf16(AH_, BL[ks_][g], acc[g], 0, 0, 0); \
        acc[g] = __builtin_amdgcn_mfma_f32_16x16x32_bf16(AL_, BH[ks_][g], acc[g], 0, 0, 0); \
      }
      WAITV(6);
      COMP(AH0, AL0, 0)
      WAITV(4);
      COMP(AH1, AL1, 1)
      WAITV(2);
      COMP(AH2, AL2, 2)
      WAITV(0);
      COMP(AH3, AL3, 3)
#undef COMP

      // ---- K-segment partials -> LDS, lane-major (conflict-free b128) ----
#pragma unroll
      for (int g = 0; g < 3; ++g)
        *(f32x4*)&part[w][g][lane][0] = acc[g];

      __syncthreads();   // parts visible; all waves' A-loads consumed

      if (epi) {
        // output (row ebl, col eul): producer lane (ebl>>2)*16+eul, elem ebl&3
        const int pl = (ebl >> 2) * 16 + eul, pe = ebl & 3;
        float sz = 0.f, sr = 0.f, sh = 0.f;
#pragma unroll
        for (int ss = 0; ss < 8; ++ss) {
          sz += part[ss][0][pl][pe];
          sr += part[ss][1][pl][pe];
          sh += part[ss][2][pl][pe];
        }

        // ---- fused gate epilogue (xq prefetched one step earlier) ----
        const float hz = sz + brz, hr = sr + brr, hhv = sh + brh;
        const float xz = (float)xq[c][0] * XP_INV;
        const float xr = (float)xq[c][1] * XP_INV;
        const float xh = (float)xq[c][2] * XP_INV;
        const float z = 1.f / (1.f + __expf(-(xz + hz)));
        const float r = 1.f / (1.f + __expf(-(xr + hr)));
        const float ca = xh + r * hhv;
        const float cand = 1.f - 2.f / (__expf(2.f * ca) + 1.f);   // tanh
        float hn = z * hp[c] + (1.f - z) * cand;
        hn = (xtok[c] != 0) ? hn : hp[c];
        hp[c] = hn;

        const int eb = b0c + ebl;
        // ordered stores: out, hHI, hLO (drain set); then 4 xq prefetches.
        stg_u32(&out[((size_t)eb * T_LEN + t) * U_DIM + eu], hn);
        const ushort_t hi = f2bf(hn);
        const ushort_t lo = f2bf(hn - bf2f(hi));
        stg_cohere_u16(wrH + (size_t)eb * U_DIM + eu, (unsigned)hi);
        stg_cohere_u16(wrL + (size_t)eb * U_DIM + eu, (unsigned)lo);

        const int tp = (t < T_LEN - 1) ? t + 1 : t;
        xq[c][0] = ldg_sshort(xp + ((size_t)tp * B_SZ + eb) * G3 + eu);
        xq[c][1] = ldg_sshort(xp + ((size_t)tp * B_SZ + eb) * G3 + 1024 + eu);
        xq[c][2] = ldg_sshort(xp + ((size_t)tp * B_SZ + eb) * G3 + 2048 + eu);
        xtok[c]  = ldg_s32(x + eb * T_LEN + tp);
        WAITV(4);   // retires the 3 stores -> h visible at MALL; xq flying
      }

      __syncthreads();   // both epi waves drained
      if (tid == 0)
        __hip_atomic_fetch_add(mycnt, 1u, __ATOMIC_RELAXED, __HIP_MEMORY_SCOPE_AGENT);
      __builtin_amdgcn_sched_barrier(0);
    }
  }

  // final state = hp (exact register carry), both chains
  if (epi) {
#pragma unroll
    for (int c = 0; c < 2; ++c)
      out[(size_t)B_SZ * T_LEN * U_DIM + (size_t)(b0 + c * 8 + ebl) * U_DIM + eu] = hp[c];
  }
}

// ---------------- launch
extern "C" void kernel_launch(void* const* d_in, const int* in_sizes, int n_in,
                              void* d_out, int out_size, void* d_ws, size_t ws_size,
                              hipStream_t stream) {
  const int*   x      = (const int*)  d_in[0];
  const float* hidden = (const float*)d_in[1];
  const float* emb    = (const float*)d_in[2];
  const float* Wx     = (const float*)d_in[3];
  const float* Wh     = (const float*)d_in[4];
  const float* b_i    = (const float*)d_in[5];
  const float* b_r    = (const float*)d_in[6];
  float* out = (float*)d_out;

  const size_t XP_B = (size_t)T_LEN * B_SZ * G3 * 2;   // 201,326,592 (int16)
  const size_t NEED = XP_B + 8 * (size_t)BU + 2048;    // + h planes + counters
  if (ws_size < NEED) return;

  short*    xp  = (short*)d_ws;
  ushort_t* hHI = (ushort_t*)((char*)d_ws + XP_B);     // [2][BU] bf16-hi
  ushort_t* hLO = hHI + 2 * (size_t)BU;                // [2][BU] bf16-lo
  unsigned* cnt = (unsigned*)(hLO + 2 * (size_t)BU);   // 8 counters, 256B apart

  init_h<<<BU / 256, 256, 0, stream>>>(hidden, hHI, hLO, cnt);
  gemm_xp<<<(32768 / 128) * (G3 / 128), 256, 0, stream>>>(emb, Wx, x, b_i, xp);
  gru_scan<<<NWG, 512, 0, stream>>>(hidden, Wh, b_r, xp, x, hHI, hLO, cnt, out);
}

// Round 8
// 3768.456 us; speedup vs baseline: 1.1372x; 1.1372x over previous
//
#include <hip/hip_runtime.h>
#include <stdint.h>

// GRU encoder: B=64 T=512 U=E=1024 V=32000, gates z|r|h, reset_after=True.
// Round-14 structure:
//   Phase 0: init_h  — quantize hidden -> int16 h-plane, zero 256 flags.
//   Phase 1: gemm_xp — unchanged proven kernel: xp int16 @2^17.
//   Phase 2: gru_scan — persistent, 256 WGs x 512 thr (r11 data path, best
//     known 2353us scan), with the group barrier replaced by FINE-GRAINED
//     producer->consumer flags:
//     r13 post-mortem: paired chains doubled MFMA work, phases serialized
//     -> regression. Reverted. r11 residual = barrier protocol: serialized
//     64-atomic + single sleepy poller + release sync + max-of-64 skew.
//     r14: wave w consumes h cols [128w,128w+128) = produced by exactly 8
//     WGs (uj=8w..8w+7). Each WG publishes flags[bi][uj]=t+1 (plain sc0sc1
//     store, no RMW) after sync(1)[reads consumed] + WAITV[stores drained]
//     + sync(2). Each wave INDEPENDENTLY polls its own 8 flags (8 dwords,
//     ballot, s_sleep(1) — bounded traffic, not r10's storm). No atomic,
//     no release sync; slow producer delays only dependent waves. WAR safe:
//     h(t+1) writes happen after all 8 waves polled >= t => all 64 group
//     WGs finished t-1 => old-buffer readers done (2 buffers suffice).
// ws: xp 201.33MB | h16 2x128KB | flags 1KB = 201.58MB.

#define B_SZ   64
#define T_LEN  512
#define U_DIM  1024
#define E_DIM  1024
#define G3     3072
#define BU     (B_SZ * U_DIM)
#define XP_SCALE 131072.0f
#define XP_INV   (1.0f / 131072.0f)
#define H_SCALE  32768.0f
#define H_INV    (1.0f / 32768.0f)
#define LDT    40   // gemm LDS row stride (ushorts): 80B, 16B-aligned
#define NWG    256

typedef unsigned short ushort_t;
typedef __attribute__((ext_vector_type(8))) short bf16x8;
typedef __attribute__((ext_vector_type(4))) float f32x4;

__device__ __forceinline__ ushort_t f2bf(float f) {
  unsigned u = __builtin_bit_cast(unsigned, f);
  u += 0x7fffu + ((u >> 16) & 1u);          // RNE
  return (ushort_t)(u >> 16);
}
__device__ __forceinline__ float bf2f(ushort_t h) {
  return __builtin_bit_cast(float, (unsigned)h << 16);
}

// ---- coherent (MALL-point) memory ops: bypass L1+L2 via sc0 sc1 ----
__device__ __forceinline__ bf16x8 ldg_cohere_b128(const void* p) {
  bf16x8 r;
  asm volatile("global_load_dwordx4 %0, %1, off sc0 sc1"
               : "=v"(r) : "v"(p) : "memory");
  return r;
}
__device__ __forceinline__ void stg_cohere_u16(short* p, unsigned v) {
  asm volatile("global_store_short %0, %1, off sc0 sc1"
               :: "v"(p), "v"(v) : "memory");
}
__device__ __forceinline__ void stg_cohere_u32(unsigned* p, unsigned v) {
  asm volatile("global_store_dword %0, %1, off sc0 sc1"
               :: "v"(p), "v"(v) : "memory");
}
__device__ __forceinline__ unsigned ldg_cohere_u32(const unsigned* p) {
  unsigned r;
  asm volatile("global_load_dword %0, %1, off sc0 sc1\n\ts_waitcnt vmcnt(0)"
               : "=v"(r) : "v"(p) : "memory");
  return r;
}
// ---- ordinary cached ops, but as ordered volatile asm (vmcnt counting) ----
__device__ __forceinline__ int ldg_sshort(const short* p) {
  int r;
  asm volatile("global_load_sshort %0, %1, off"
               : "=v"(r) : "v"(p) : "memory");
  return r;
}
__device__ __forceinline__ int ldg_s32(const int* p) {
  int r;
  asm volatile("global_load_dword %0, %1, off"
               : "=v"(r) : "v"(p) : "memory");
  return r;
}
__device__ __forceinline__ void stg_u32(float* p, float v) {
  asm volatile("global_store_dword %0, %1, off"
               :: "v"(p), "v"(v) : "memory");
}
#define WAITV(n) do { asm volatile("s_waitcnt vmcnt(" #n ")" ::: "memory"); \
                      __builtin_amdgcn_sched_barrier(0); } while (0)

// ---------------- Phase 1: gathered GEMM, 128x128 tile, BK=32, 4 waves,
// split-bf16, 41KB pure-static LDS (unchanged proven kernel).
__global__ __launch_bounds__(256) void gemm_xp(
    const float* __restrict__ emb,    // [V][1024] f32 (gathered rows)
    const float* __restrict__ Wx,     // [1024][3072] f32
    const int* __restrict__ x,        // [B*T] (m = b*T+t)
    const float* __restrict__ b_i,    // [3072]
    short* __restrict__ xp)           // [T][B][3072] int16 (x 2^17)
{
  __shared__ ushort_t aH[128 * LDT];
  __shared__ ushort_t aL[128 * LDT];
  __shared__ ushort_t bH[128 * LDT];
  __shared__ ushort_t bL[128 * LDT];
  const int tid = threadIdx.x, lane = tid & 63, w = tid >> 6;
  const int bx = blockIdx.x;
  const int nIdx = bx % 24, mIdx = bx / 24;
  const int m0 = mIdx * 128, n0 = nIdx * 128;

  const int aRow0 = tid >> 2, aRow1 = (tid + 256) >> 2, aKoct = tid & 3;
  const size_t aBase0 = (size_t)x[m0 + aRow0] * E_DIM + (size_t)aKoct * 8;
  const size_t aBase1 = (size_t)x[m0 + aRow1] * E_DIM + (size_t)aKoct * 8;
  const int bN = tid & 127, bKoct0 = tid >> 7;

  const int wr = (w >> 1) * 64, wc = (w & 1) * 64;
  f32x4 acc[4][4];
#pragma unroll
  for (int i = 0; i < 4; i++)
#pragma unroll
    for (int j = 0; j < 4; j++) acc[i][j] = (f32x4){0.f, 0.f, 0.f, 0.f};

  for (int k0 = 0; k0 < E_DIM; k0 += 32) {
    __syncthreads();
#pragma unroll
    for (int pp = 0; pp < 2; ++pp) {
      const float* src = emb + (pp ? aBase1 : aBase0) + k0;
      int row = pp ? aRow1 : aRow0;
      float4 v0 = *(const float4*)(src);
      float4 v1 = *(const float4*)(src + 4);
      float vv[8] = {v0.x, v0.y, v0.z, v0.w, v1.x, v1.y, v1.z, v1.w};
      bf16x8 oh, ol;
#pragma unroll
      for (int j = 0; j < 8; ++j) {
        ushort_t hi = f2bf(vv[j]);
        oh[j] = (short)hi;
        ol[j] = (short)f2bf(vv[j] - bf2f(hi));
      }
      int off = row * LDT + aKoct * 8;
      *(bf16x8*)&aH[off] = oh;
      *(bf16x8*)&aL[off] = ol;
    }
#pragma unroll
    for (int kk = 0; kk < 2; ++kk) {
      int koct = bKoct0 + 2 * kk;
      float vv[8];
#pragma unroll
      for (int e = 0; e < 8; ++e)
        vv[e] = Wx[(size_t)(k0 + koct * 8 + e) * G3 + n0 + bN];
      bf16x8 oh, ol;
#pragma unroll
      for (int j = 0; j < 8; ++j) {
        ushort_t hi = f2bf(vv[j]);
        oh[j] = (short)hi;
        ol[j] = (short)f2bf(vv[j] - bf2f(hi));
      }
      int off = bN * LDT + koct * 8;
      *(bf16x8*)&bH[off] = oh;
      *(bf16x8*)&bL[off] = ol;
    }
    __syncthreads();
    bf16x8 afH[4], afL[4], bfH[4], bfL[4];
#pragma unroll
    for (int mi = 0; mi < 4; mi++) {
      int off = (wr + mi * 16 + (lane & 15)) * LDT + (lane >> 4) * 8;
      afH[mi] = *(const bf16x8*)&aH[off];
      afL[mi] = *(const bf16x8*)&aL[off];
    }
#pragma unroll
    for (int ni = 0; ni < 4; ni++) {
      int off = (wc + ni * 16 + (lane & 15)) * LDT + (lane >> 4) * 8;
      bfH[ni] = *(const bf16x8*)&bH[off];
      bfL[ni] = *(const bf16x8*)&bL[off];
    }
#pragma unroll
    for (int mi = 0; mi < 4; mi++)
#pragma unroll
      for (int ni = 0; ni < 4; ni++) {
        acc[mi][ni] = __builtin_amdgcn_mfma_f32_16x16x32_bf16(afH[mi], bfH[ni], acc[mi][ni], 0, 0, 0);
        acc[mi][ni] = __builtin_amdgcn_mfma_f32_16x16x32_bf16(afH[mi], bfL[ni], acc[mi][ni], 0, 0, 0);
        acc[mi][ni] = __builtin_amdgcn_mfma_f32_16x16x32_bf16(afL[mi], bfH[ni], acc[mi][ni], 0, 0, 0);
      }
  }
#pragma unroll
  for (int ni = 0; ni < 4; ni++) {
    int col = n0 + wc + ni * 16 + (lane & 15);
    float bias = b_i[col];
#pragma unroll
    for (int mi = 0; mi < 4; mi++) {
      int rbase = m0 + wr + mi * 16 + (lane >> 4) * 4;
#pragma unroll
      for (int i = 0; i < 4; i++) {
        int m = rbase + i;
        int b = m >> 9, t = m & 511;
        float v = acc[mi][ni][i] + bias;
        int q = __float2int_rn(v * XP_SCALE);
        q = q > 32767 ? 32767 : (q < -32768 ? -32768 : q);
        xp[(size_t)(t * 64 + b) * G3 + col] = (short)q;
      }
    }
  }
}

// ---------------- Phase 0: quantize hidden -> int16 h-plane (buffer 0),
// zero the 256 producer flags. Runs every launch.
__global__ __launch_bounds__(256) void init_h(
    const float* __restrict__ hidden,
    short* __restrict__ h16,
    unsigned* __restrict__ flags)
{
  const int i = blockIdx.x * 256 + threadIdx.x;
  if (blockIdx.x == 0) flags[threadIdx.x] = 0u;
  if (i < BU) {
    int q = __float2int_rn(hidden[i] * H_SCALE);
    q = q > 32767 ? 32767 : (q < -32768 ? -32768 : q);
    h16[i] = (short)q;
  }
}

// ---------------- Phase 2: persistent GRU scan, dataflow-flag sync.
// WG(bx): uj = bx&63 (u-tile of 16), bi = bx>>6 (batch-group of 16 rows).
// Wave w (0..7) owns K-segment [128w,128w+128). Verified MFMA layouts:
// A row=lane&15 k=(lane>>4)*8+j; B col=lane&15 same k; C row=(lane>>4)*4+i
// col=lane&15. h exchanged as int16 @2^15 (one plane, double-buffered);
// unpacked to EXACT split-bf16 in VALU. Sync: flags[bi][uj]=t+1 published
// by tid0 after {sync(1): all reads consumed} + {WAITV: h stores at MALL}
// + {sync(2)}. Wave w polls only flags[bi][8w..8w+7] (RAW+WAR safe, see
// header). 2 syncthreads/step, zero atomics.
__global__ __launch_bounds__(512) void gru_scan(
    const float* __restrict__ hidden,  // [64][1024] f32 (hp init)
    const float* __restrict__ Wh,      // [1024][3072] f32
    const float* __restrict__ b_r,     // [3072]
    const short* __restrict__ xp,      // [T][64][3072] int16
    const int* __restrict__ x,         // [64][512]
    short* __restrict__ h16,           // [2][64][1024] int16 @2^15
    unsigned* __restrict__ flags,      // [4][64] producer flags
    float* __restrict__ out)           // [64][512][1024] f32 + [64][1024] state
{
  __shared__ float part[8][3][64][4];   // [kseg][gate][lane][elem] 24KB
  const int tid  = threadIdx.x;
  const int lane = tid & 63;
  const int w    = tid >> 6;            // wave id = K-segment
  const int bx   = (int)blockIdx.x;
  const int uj   = bx & 63, bi = bx >> 6;
  const int u0   = uj * 16, b0 = bi * 16;
  const int c16  = lane & 15;           // fragment row/col-within-tile
  const int kg   = lane >> 4;           // k-group (x8)
  unsigned* gflags = flags + bi * 64;           // this group's 64 flags
  const unsigned* pollp = gflags + 8 * w + (lane & 7);  // this wave's 8

  // ---- Wh fragments resident in registers (built once, cached loads) ----
  bf16x8 BH[4][3], BL[4][3];
#pragma unroll
  for (int ks = 0; ks < 4; ++ks)
#pragma unroll
    for (int g = 0; g < 3; ++g) {
      bf16x8 bh, bl;
#pragma unroll
      for (int j = 0; j < 8; ++j) {
        int k = w * 128 + ks * 32 + kg * 8 + j;
        float v = Wh[(size_t)k * G3 + g * 1024 + u0 + c16];
        ushort_t hi = f2bf(v);
        bh[j] = (short)hi;
        bl[j] = (short)f2bf(v - bf2f(hi));
      }
      BH[ks][g] = bh;
      BL[ks][g] = bl;
    }

  // ---- epilogue ownership: waves 0-3 (tid<256): one (b,u) per thread ----
  const bool epi = (tid < 256);
  const int ebl = (tid >> 4) & 15, eul = tid & 15;
  const int eb = b0 + ebl, eu = u0 + eul;
  float brz = 0.f, brr = 0.f, brh = 0.f, hp = 0.f;
  if (epi) {
    brz = b_r[eu]; brr = b_r[1024 + eu]; brh = b_r[2048 + eu];
    hp  = hidden[(size_t)eb * U_DIM + eu];
  }

  // drain everything before entering the counted-vmcnt regime
  asm volatile("s_waitcnt vmcnt(0) lgkmcnt(0)" ::: "memory");

  // prologue: prefetch xq for t=0 (epi waves carry 4 extra in-flight loads;
  // every WAITV below is FIFO oldest-first and correct for both wave classes;
  // the poll's internal vmcnt(0) merely retires them early).
  int xq0 = 0, xq1 = 0, xq2 = 0, xtok = 0;
  if (epi) {
    xq0 = ldg_sshort(xp + (size_t)eb * G3 + eu);
    xq1 = ldg_sshort(xp + (size_t)eb * G3 + 1024 + eu);
    xq2 = ldg_sshort(xp + (size_t)eb * G3 + 2048 + eu);
    xtok = ldg_s32(x + eb * T_LEN + 0);
  }

  unsigned spins = 0;            // global spin budget: deadlock bails visibly
  for (int t = 0; t < T_LEN; ++t) {
    const short* __restrict__ rP = h16 + (size_t)(t & 1) * BU;
    short* __restrict__ wP       = h16 + (size_t)((t + 1) & 1) * BU;

    // ---- per-wave dataflow wait: this wave's 8 producers at step >= t ----
    if (t > 0) {
      const unsigned tgt = (unsigned)t;
      while (spins < (1u << 22)) {
        unsigned f = ldg_cohere_u32(pollp);   // lanes dup (lane&7): 32B/poll
        if (__ballot(f >= tgt) == ~0ull) break;
        __builtin_amdgcn_s_sleep(1);
        ++spins;
      }
    }

    // A rows = this group's 16 h-rows; row c16, k-base w*128 + kg*8
    const short* pP = rP + (size_t)(b0 + c16) * U_DIM + w * 128 + kg * 8;

    f32x4 acc[3];
#pragma unroll
    for (int g = 0; g < 3; ++g) acc[g] = (f32x4){0.f, 0.f, 0.f, 0.f};

    // issue all 4 packed A-loads upfront; FIFO waits (t=0 epi has +4 older
    // xq; t>0 queue starts empty after poll — counts valid either way):
    //   WAITV(3)->P0 done, WAITV(2)->P1, WAITV(1)->P2, WAITV(0)->P3.
    bf16x8 P0, P1, P2, P3;
    P0 = ldg_cohere_b128(pP + 0 * 32);
    P1 = ldg_cohere_b128(pP + 1 * 32);
    P2 = ldg_cohere_b128(pP + 2 * 32);
    P3 = ldg_cohere_b128(pP + 3 * 32);

    // unpack int16 -> EXACT split bf16 (hi 8 mant bits + lo rest), then MFMA
#define UNPCK(P_, AH_, AL_) \
    { \
      _Pragma("unroll") \
      for (int j = 0; j < 8; ++j) { \
        float v = (float)(short)P_[j] * H_INV; \
        ushort_t hi = f2bf(v); \
        AH_[j] = (short)hi; \
        AL_[j] = (short)f2bf(v - bf2f(hi)); \
      } \
    }
#define COMP(AH_, AL_, ks_) \
    _Pragma("unroll") \
    for (int g = 0; g < 3; ++g) { \
      acc[g] = __builtin_amdgcn_mfma_f32_16x16x32_bf16(AH_, BH[ks_][g], acc[g], 0, 0, 0); \
      acc[g] = __builtin_amdgcn_mfma_f32_16x16x32_bf16(AH_, BL[ks_][g], acc[g], 0, 0, 0); \
      acc[g] = __builtin_amdgcn_mfma_f32_16x16x32_bf16(AL_, BH[ks_][g], acc[g], 0, 0, 0); \
    }
    bf16x8 AH, AL;
    WAITV(3);
    UNPCK(P0, AH, AL)
    COMP(AH, AL, 0)
    WAITV(2);
    UNPCK(P1, AH, AL)
    COMP(AH, AL, 1)
    WAITV(1);
    UNPCK(P2, AH, AL)
    COMP(AH, AL, 2)
    WAITV(0);
    UNPCK(P3, AH, AL)
    COMP(AH, AL, 3)
#undef UNPCK
#undef COMP

    // ---- K-segment partials -> LDS, lane-major: contiguous b128 writes ----
#pragma unroll
    for (int g = 0; g < 3; ++g)
      *(f32x4*)&part[w][g][lane][0] = acc[g];

    __syncthreads();   // (1) parts visible; ALL waves' A-reads consumed

    if (epi) {
      // C elem: row ebl col eul -> producer lane (ebl>>2)*16+eul, elem ebl&3
      const int pl = (ebl >> 2) * 16 + eul, pe = ebl & 3;
      float sz = 0.f, sr = 0.f, sh = 0.f;
#pragma unroll
      for (int s = 0; s < 8; ++s) {
        sz += part[s][0][pl][pe];
        sr += part[s][1][pl][pe];
        sh += part[s][2][pl][pe];
      }

      // ---- fused gate epilogue (xq values prefetched last iteration) ----
      const float hz = sz + brz, hr = sr + brr, hhv = sh + brh;
      const float xz = (float)xq0 * XP_INV;
      const float xr = (float)xq1 * XP_INV;
      const float xh = (float)xq2 * XP_INV;
      const float z = 1.f / (1.f + __expf(-(xz + hz)));
      const float r = 1.f / (1.f + __expf(-(xr + hr)));
      const float ca = xh + r * hhv;
      const float cand = 1.f - 2.f / (__expf(2.f * ca) + 1.f);   // tanh
      float hn = z * hp + (1.f - z) * cand;
      hn = (xtok != 0) ? hn : hp;
      hp = hn;

      // ordered stores: out (1), h16 (2); then 4 xq prefetches; WAITV(4)
      // drains exactly [out, h16] -> h visible at MALL; xq still flying.
      stg_u32(&out[((size_t)eb * T_LEN + t) * U_DIM + eu], hn);
      int q = __float2int_rn(hn * H_SCALE);
      q = q > 32767 ? 32767 : (q < -32768 ? -32768 : q);
      stg_cohere_u16(wP + (size_t)eb * U_DIM + eu, (unsigned)q);

      const int tp = (t < T_LEN - 1) ? t + 1 : t;
      xq0 = ldg_sshort(xp + ((size_t)tp * B_SZ + eb) * G3 + eu);
      xq1 = ldg_sshort(xp + ((size_t)tp * B_SZ + eb) * G3 + 1024 + eu);
      xq2 = ldg_sshort(xp + ((size_t)tp * B_SZ + eb) * G3 + 2048 + eu);
      xtok = ldg_s32(x + eb * T_LEN + tp);
      WAITV(4);
    }

    __syncthreads();   // (2) epi stores drained; whole WG done with step t
    if (tid == 0)
      stg_cohere_u32(gflags + uj, (unsigned)(t + 1));   // publish (no RMW)
    __builtin_amdgcn_sched_barrier(0);
  }

  // final state = hp (exact register carry)
  if (epi)
    out[(size_t)B_SZ * T_LEN * U_DIM + (size_t)eb * U_DIM + eu] = hp;
}

// ---------------- launch
extern "C" void kernel_launch(void* const* d_in, const int* in_sizes, int n_in,
                              void* d_out, int out_size, void* d_ws, size_t ws_size,
                              hipStream_t stream) {
  const int*   x      = (const int*)  d_in[0];
  const float* hidden = (const float*)d_in[1];
  const float* emb    = (const float*)d_in[2];
  const float* Wx     = (const float*)d_in[3];
  const float* Wh     = (const float*)d_in[4];
  const float* b_i    = (const float*)d_in[5];
  const float* b_r    = (const float*)d_in[6];
  float* out = (float*)d_out;

  const size_t XP_B = (size_t)T_LEN * B_SZ * G3 * 2;   // 201,326,592 (int16)
  const size_t NEED = XP_B + 4 * (size_t)BU + 1024;    // + h16 x2 + flags
  if (ws_size < NEED) return;

  short*    xp    = (short*)d_ws;
  short*    h16   = (short*)((char*)d_ws + XP_B);      // [2][BU] int16
  unsigned* flags = (unsigned*)(h16 + 2 * (size_t)BU); // [4][64] u32

  init_h<<<BU / 256, 256, 0, stream>>>(hidden, h16, flags);
  gemm_xp<<<(32768 / 128) * (G3 / 128), 256, 0, stream>>>(emb, Wx, x, b_i, xp);
  gru_scan<<<NWG, 512, 0, stream>>>(hidden, Wh, b_r, xp, x, h16, flags, out);
}

// Round 9
// 2909.695 us; speedup vs baseline: 1.4729x; 1.2951x over previous
//
#include <hip/hip_runtime.h>
#include <stdint.h>

// GRU encoder: B=64 T=512 U=E=1024 V=32000, gates z|r|h, reset_after=True.
// Round-15 structure (r11 + parallel-flag arrival, clean A/B):
//   Phase 0: init_h  — quantize hidden -> int16 h-plane, zero 4096 flag words.
//   Phase 1: gemm_xp — unchanged proven kernel: xp int16 @2^17.
//   Phase 2: gru_scan — persistent, 256 WGs x 512 thr, r11 data path
//     (int16 h @2^15, counted-vmcnt ladder, lane-major part, 3 syncs/step).
//     r14 post-mortem: per-wave flags regressed via poll mechanics (2048
//     pollers, VALU 21%), not the dataflow idea. r11 residual theory: the
//     64 near-simultaneous fetch_adds to ONE MALL line serialize (~2-4k cy
//     tail on the critical path). r15 isolates ONLY that term:
//       - arrival: tid0 plain sc0sc1 store to the WG's OWN flag word,
//         padded to its own 64B line (no RMW, no line contention).
//       - detection: unchanged single wave-0 poller; 64 lanes read the 64
//         flags (one load/lane/iter), ballot, s_sleep(2).
//       - everything else byte-identical to r11 (best known: 2353us scan).
//     If step stays ~4.6us: both arrival mechanisms equal -> structural
//     floor of the 256-WG MALL recurrence; declare roofline next round.
// ws: xp 201.33MB | h16 2x128KB | flags 16KB = 201.60MB.

#define B_SZ   64
#define T_LEN  512
#define U_DIM  1024
#define E_DIM  1024
#define G3     3072
#define BU     (B_SZ * U_DIM)
#define XP_SCALE 131072.0f
#define XP_INV   (1.0f / 131072.0f)
#define H_SCALE  32768.0f
#define H_INV    (1.0f / 32768.0f)
#define LDT    40   // gemm LDS row stride (ushorts): 80B, 16B-aligned
#define NWG    256

typedef unsigned short ushort_t;
typedef __attribute__((ext_vector_type(8))) short bf16x8;
typedef __attribute__((ext_vector_type(4))) float f32x4;

__device__ __forceinline__ ushort_t f2bf(float f) {
  unsigned u = __builtin_bit_cast(unsigned, f);
  u += 0x7fffu + ((u >> 16) & 1u);          // RNE
  return (ushort_t)(u >> 16);
}
__device__ __forceinline__ float bf2f(ushort_t h) {
  return __builtin_bit_cast(float, (unsigned)h << 16);
}

// ---- coherent (MALL-point) memory ops: bypass L1+L2 via sc0 sc1 ----
__device__ __forceinline__ bf16x8 ldg_cohere_b128(const void* p) {
  bf16x8 r;
  asm volatile("global_load_dwordx4 %0, %1, off sc0 sc1"
               : "=v"(r) : "v"(p) : "memory");
  return r;
}
__device__ __forceinline__ void stg_cohere_u16(short* p, unsigned v) {
  asm volatile("global_store_short %0, %1, off sc0 sc1"
               :: "v"(p), "v"(v) : "memory");
}
__device__ __forceinline__ void stg_cohere_u32(unsigned* p, unsigned v) {
  asm volatile("global_store_dword %0, %1, off sc0 sc1"
               :: "v"(p), "v"(v) : "memory");
}
__device__ __forceinline__ unsigned ldg_cohere_u32(const unsigned* p) {
  unsigned r;
  asm volatile("global_load_dword %0, %1, off sc0 sc1\n\ts_waitcnt vmcnt(0)"
               : "=v"(r) : "v"(p) : "memory");
  return r;
}
// ---- ordinary cached ops, but as ordered volatile asm (vmcnt counting) ----
__device__ __forceinline__ int ldg_sshort(const short* p) {
  int r;
  asm volatile("global_load_sshort %0, %1, off"
               : "=v"(r) : "v"(p) : "memory");
  return r;
}
__device__ __forceinline__ int ldg_s32(const int* p) {
  int r;
  asm volatile("global_load_dword %0, %1, off"
               : "=v"(r) : "v"(p) : "memory");
  return r;
}
__device__ __forceinline__ void stg_u32(float* p, float v) {
  asm volatile("global_store_dword %0, %1, off"
               :: "v"(p), "v"(v) : "memory");
}
#define WAITV(n) do { asm volatile("s_waitcnt vmcnt(" #n ")" ::: "memory"); \
                      __builtin_amdgcn_sched_barrier(0); } while (0)

// ---------------- Phase 1: gathered GEMM, 128x128 tile, BK=32, 4 waves,
// split-bf16, 41KB pure-static LDS (unchanged proven kernel).
__global__ __launch_bounds__(256) void gemm_xp(
    const float* __restrict__ emb,    // [V][1024] f32 (gathered rows)
    const float* __restrict__ Wx,     // [1024][3072] f32
    const int* __restrict__ x,        // [B*T] (m = b*T+t)
    const float* __restrict__ b_i,    // [3072]
    short* __restrict__ xp)           // [T][B][3072] int16 (x 2^17)
{
  __shared__ ushort_t aH[128 * LDT];
  __shared__ ushort_t aL[128 * LDT];
  __shared__ ushort_t bH[128 * LDT];
  __shared__ ushort_t bL[128 * LDT];
  const int tid = threadIdx.x, lane = tid & 63, w = tid >> 6;
  const int bx = blockIdx.x;
  const int nIdx = bx % 24, mIdx = bx / 24;
  const int m0 = mIdx * 128, n0 = nIdx * 128;

  const int aRow0 = tid >> 2, aRow1 = (tid + 256) >> 2, aKoct = tid & 3;
  const size_t aBase0 = (size_t)x[m0 + aRow0] * E_DIM + (size_t)aKoct * 8;
  const size_t aBase1 = (size_t)x[m0 + aRow1] * E_DIM + (size_t)aKoct * 8;
  const int bN = tid & 127, bKoct0 = tid >> 7;

  const int wr = (w >> 1) * 64, wc = (w & 1) * 64;
  f32x4 acc[4][4];
#pragma unroll
  for (int i = 0; i < 4; i++)
#pragma unroll
    for (int j = 0; j < 4; j++) acc[i][j] = (f32x4){0.f, 0.f, 0.f, 0.f};

  for (int k0 = 0; k0 < E_DIM; k0 += 32) {
    __syncthreads();
#pragma unroll
    for (int pp = 0; pp < 2; ++pp) {
      const float* src = emb + (pp ? aBase1 : aBase0) + k0;
      int row = pp ? aRow1 : aRow0;
      float4 v0 = *(const float4*)(src);
      float4 v1 = *(const float4*)(src + 4);
      float vv[8] = {v0.x, v0.y, v0.z, v0.w, v1.x, v1.y, v1.z, v1.w};
      bf16x8 oh, ol;
#pragma unroll
      for (int j = 0; j < 8; ++j) {
        ushort_t hi = f2bf(vv[j]);
        oh[j] = (short)hi;
        ol[j] = (short)f2bf(vv[j] - bf2f(hi));
      }
      int off = row * LDT + aKoct * 8;
      *(bf16x8*)&aH[off] = oh;
      *(bf16x8*)&aL[off] = ol;
    }
#pragma unroll
    for (int kk = 0; kk < 2; ++kk) {
      int koct = bKoct0 + 2 * kk;
      float vv[8];
#pragma unroll
      for (int e = 0; e < 8; ++e)
        vv[e] = Wx[(size_t)(k0 + koct * 8 + e) * G3 + n0 + bN];
      bf16x8 oh, ol;
#pragma unroll
      for (int j = 0; j < 8; ++j) {
        ushort_t hi = f2bf(vv[j]);
        oh[j] = (short)hi;
        ol[j] = (short)f2bf(vv[j] - bf2f(hi));
      }
      int off = bN * LDT + koct * 8;
      *(bf16x8*)&bH[off] = oh;
      *(bf16x8*)&bL[off] = ol;
    }
    __syncthreads();
    bf16x8 afH[4], afL[4], bfH[4], bfL[4];
#pragma unroll
    for (int mi = 0; mi < 4; mi++) {
      int off = (wr + mi * 16 + (lane & 15)) * LDT + (lane >> 4) * 8;
      afH[mi] = *(const bf16x8*)&aH[off];
      afL[mi] = *(const bf16x8*)&aL[off];
    }
#pragma unroll
    for (int ni = 0; ni < 4; ni++) {
      int off = (wc + ni * 16 + (lane & 15)) * LDT + (lane >> 4) * 8;
      bfH[ni] = *(const bf16x8*)&bH[off];
      bfL[ni] = *(const bf16x8*)&bL[off];
    }
#pragma unroll
    for (int mi = 0; mi < 4; mi++)
#pragma unroll
      for (int ni = 0; ni < 4; ni++) {
        acc[mi][ni] = __builtin_amdgcn_mfma_f32_16x16x32_bf16(afH[mi], bfH[ni], acc[mi][ni], 0, 0, 0);
        acc[mi][ni] = __builtin_amdgcn_mfma_f32_16x16x32_bf16(afH[mi], bfL[ni], acc[mi][ni], 0, 0, 0);
        acc[mi][ni] = __builtin_amdgcn_mfma_f32_16x16x32_bf16(afL[mi], bfH[ni], acc[mi][ni], 0, 0, 0);
      }
  }
#pragma unroll
  for (int ni = 0; ni < 4; ni++) {
    int col = n0 + wc + ni * 16 + (lane & 15);
    float bias = b_i[col];
#pragma unroll
    for (int mi = 0; mi < 4; mi++) {
      int rbase = m0 + wr + mi * 16 + (lane >> 4) * 4;
#pragma unroll
      for (int i = 0; i < 4; i++) {
        int m = rbase + i;
        int b = m >> 9, t = m & 511;
        float v = acc[mi][ni][i] + bias;
        int q = __float2int_rn(v * XP_SCALE);
        q = q > 32767 ? 32767 : (q < -32768 ? -32768 : q);
        xp[(size_t)(t * 64 + b) * G3 + col] = (short)q;
      }
    }
  }
}

// ---------------- Phase 0: quantize hidden -> int16 h-plane (buffer 0),
// zero the 4096 flag words (4 groups x 64 flags x 16-dword stride).
__global__ __launch_bounds__(256) void init_h(
    const float* __restrict__ hidden,
    short* __restrict__ h16,
    unsigned* __restrict__ flags)
{
  const int i = blockIdx.x * 256 + threadIdx.x;
  if (blockIdx.x < 16) flags[blockIdx.x * 256 + threadIdx.x] = 0u;
  if (i < BU) {
    int q = __float2int_rn(hidden[i] * H_SCALE);
    q = q > 32767 ? 32767 : (q < -32768 ? -32768 : q);
    h16[i] = (short)q;
  }
}

// ---------------- Phase 2: persistent GRU scan, parallel-flag barrier.
// WG(bx): uj = bx&63 (u-tile of 16), bi = bx>>6 (batch-group of 16 rows).
// Wave w (0..7) owns K-segment [128w,128w+128). Verified MFMA layouts:
// A row=lane&15 k=(lane>>4)*8+j; B col=lane&15 same k; C row=(lane>>4)*4+i
// col=lane&15. h exchanged as int16 @2^15 (one plane, double-buffered);
// unpacked to EXACT split-bf16 in VALU. Barrier: arrival = tid0 plain
// sc0sc1 store to own 64B-padded flag (after sync(1) reads-consumed +
// WAITV stores-drained + sync(2)); detection = wave-0, 64 lanes read the
// 64 group flags, ballot>=t, s_sleep(2); then __syncthreads release.
__global__ __launch_bounds__(512) void gru_scan(
    const float* __restrict__ hidden,  // [64][1024] f32 (hp init)
    const float* __restrict__ Wh,      // [1024][3072] f32
    const float* __restrict__ b_r,     // [3072]
    const short* __restrict__ xp,      // [T][64][3072] int16
    const int* __restrict__ x,         // [64][512]
    short* __restrict__ h16,           // [2][64][1024] int16 @2^15
    unsigned* __restrict__ flags,      // [4][64][16] u32 (flag per 64B line)
    float* __restrict__ out)           // [64][512][1024] f32 + [64][1024] state
{
  __shared__ float part[8][3][64][4];   // [kseg][gate][lane][elem] 24KB
  const int tid  = threadIdx.x;
  const int lane = tid & 63;
  const int w    = tid >> 6;            // wave id = K-segment
  const int bx   = (int)blockIdx.x;
  const int uj   = bx & 63, bi = bx >> 6;
  const int u0   = uj * 16, b0 = bi * 16;
  const int c16  = lane & 15;           // fragment row/col-within-tile
  const int kg   = lane >> 4;           // k-group (x8)
  unsigned* gflags = flags + bi * 1024;         // this group's 64 flag lines
  const unsigned* pollp = gflags + lane * 16;   // wave-0 lane -> one flag

  // ---- Wh fragments resident in registers (built once, cached loads) ----
  bf16x8 BH[4][3], BL[4][3];
#pragma unroll
  for (int ks = 0; ks < 4; ++ks)
#pragma unroll
    for (int g = 0; g < 3; ++g) {
      bf16x8 bh, bl;
#pragma unroll
      for (int j = 0; j < 8; ++j) {
        int k = w * 128 + ks * 32 + kg * 8 + j;
        float v = Wh[(size_t)k * G3 + g * 1024 + u0 + c16];
        ushort_t hi = f2bf(v);
        bh[j] = (short)hi;
        bl[j] = (short)f2bf(v - bf2f(hi));
      }
      BH[ks][g] = bh;
      BL[ks][g] = bl;
    }

  // ---- epilogue ownership: waves 0-3 (tid<256): one (b,u) per thread ----
  const bool epi = (tid < 256);
  const int ebl = (tid >> 4) & 15, eul = tid & 15;
  const int eb = b0 + ebl, eu = u0 + eul;
  float brz = 0.f, brr = 0.f, brh = 0.f, hp = 0.f;
  if (epi) {
    brz = b_r[eu]; brr = b_r[1024 + eu]; brh = b_r[2048 + eu];
    hp  = hidden[(size_t)eb * U_DIM + eu];
  }

  // drain everything before entering the counted-vmcnt regime
  asm volatile("s_waitcnt vmcnt(0) lgkmcnt(0)" ::: "memory");

  // prologue: prefetch xq for t=0 (epi waves carry 4 extra in-flight loads;
  // every WAITV below is FIFO oldest-first and correct for both wave classes;
  // wave-0's poll vmcnt(0) merely retires its prefetches early).
  int xq0 = 0, xq1 = 0, xq2 = 0, xtok = 0;
  if (epi) {
    xq0 = ldg_sshort(xp + (size_t)eb * G3 + eu);
    xq1 = ldg_sshort(xp + (size_t)eb * G3 + 1024 + eu);
    xq2 = ldg_sshort(xp + (size_t)eb * G3 + 2048 + eu);
    xtok = ldg_s32(x + eb * T_LEN + 0);
  }

  unsigned spins = 0;            // global spin budget: deadlock bails visibly
  for (int t = 0; t < T_LEN; ++t) {
    const short* __restrict__ rP = h16 + (size_t)(t & 1) * BU;
    short* __restrict__ wP       = h16 + (size_t)((t + 1) & 1) * BU;

    // ---- barrier wait: all 64 group flags >= t (wave 0), then release ----
    if (t > 0) {
      if (w == 0) {
        const unsigned tgt = (unsigned)t;
        while (spins < (1u << 22)) {
          unsigned f = ldg_cohere_u32(pollp);   // 64 lanes -> 64 flags
          if (__ballot(f >= tgt) == ~0ull) break;
          __builtin_amdgcn_s_sleep(2);
          ++spins;
        }
      }
      __syncthreads();   // release: h(t) fully MALL-visible
    }

    // A rows = this group's 16 h-rows; row c16, k-base w*128 + kg*8
    const short* pP = rP + (size_t)(b0 + c16) * U_DIM + w * 128 + kg * 8;

    f32x4 acc[3];
#pragma unroll
    for (int g = 0; g < 3; ++g) acc[g] = (f32x4){0.f, 0.f, 0.f, 0.f};

    // issue all 4 packed A-loads upfront; FIFO waits (epi t=0 has +4 older
    // xq; wave0 queue empty after poll; non-epi 4 outstanding — all valid):
    //   WAITV(3)->P0 done, WAITV(2)->P1, WAITV(1)->P2, WAITV(0)->P3.
    bf16x8 P0, P1, P2, P3;
    P0 = ldg_cohere_b128(pP + 0 * 32);
    P1 = ldg_cohere_b128(pP + 1 * 32);
    P2 = ldg_cohere_b128(pP + 2 * 32);
    P3 = ldg_cohere_b128(pP + 3 * 32);

    // unpack int16 -> EXACT split bf16 (hi 8 mant bits + lo rest), then MFMA
#define UNPCK(P_, AH_, AL_) \
    { \
      _Pragma("unroll") \
      for (int j = 0; j < 8; ++j) { \
        float v = (float)(short)P_[j] * H_INV; \
        ushort_t hi = f2bf(v); \
        AH_[j] = (short)hi; \
        AL_[j] = (short)f2bf(v - bf2f(hi)); \
      } \
    }
#define COMP(AH_, AL_, ks_) \
    _Pragma("unroll") \
    for (int g = 0; g < 3; ++g) { \
      acc[g] = __builtin_amdgcn_mfma_f32_16x16x32_bf16(AH_, BH[ks_][g], acc[g], 0, 0, 0); \
      acc[g] = __builtin_amdgcn_mfma_f32_16x16x32_bf16(AH_, BL[ks_][g], acc[g], 0, 0, 0); \
      acc[g] = __builtin_amdgcn_mfma_f32_16x16x32_bf16(AL_, BH[ks_][g], acc[g], 0, 0, 0); \
    }
    bf16x8 AH, AL;
    WAITV(3);
    UNPCK(P0, AH, AL)
    COMP(AH, AL, 0)
    WAITV(2);
    UNPCK(P1, AH, AL)
    COMP(AH, AL, 1)
    WAITV(1);
    UNPCK(P2, AH, AL)
    COMP(AH, AL, 2)
    WAITV(0);
    UNPCK(P3, AH, AL)
    COMP(AH, AL, 3)
#undef UNPCK
#undef COMP

    // ---- K-segment partials -> LDS, lane-major: contiguous b128 writes ----
#pragma unroll
    for (int g = 0; g < 3; ++g)
      *(f32x4*)&part[w][g][lane][0] = acc[g];

    __syncthreads();   // (1) parts visible; ALL waves' A-reads consumed

    if (epi) {
      // C elem: row ebl col eul -> producer lane (ebl>>2)*16+eul, elem ebl&3
      const int pl = (ebl >> 2) * 16 + eul, pe = ebl & 3;
      float sz = 0.f, sr = 0.f, sh = 0.f;
#pragma unroll
      for (int s = 0; s < 8; ++s) {
        sz += part[s][0][pl][pe];
        sr += part[s][1][pl][pe];
        sh += part[s][2][pl][pe];
      }

      // ---- fused gate epilogue (xq values prefetched last iteration) ----
      const float hz = sz + brz, hr = sr + brr, hhv = sh + brh;
      const float xz = (float)xq0 * XP_INV;
      const float xr = (float)xq1 * XP_INV;
      const float xh = (float)xq2 * XP_INV;
      const float z = 1.f / (1.f + __expf(-(xz + hz)));
      const float r = 1.f / (1.f + __expf(-(xr + hr)));
      const float ca = xh + r * hhv;
      const float cand = 1.f - 2.f / (__expf(2.f * ca) + 1.f);   // tanh
      float hn = z * hp + (1.f - z) * cand;
      hn = (xtok != 0) ? hn : hp;
      hp = hn;

      // ordered stores: out (1), h16 (2); then 4 xq prefetches; WAITV(4)
      // drains exactly [out, h16] -> h visible at MALL; xq still flying.
      stg_u32(&out[((size_t)eb * T_LEN + t) * U_DIM + eu], hn);
      int q = __float2int_rn(hn * H_SCALE);
      q = q > 32767 ? 32767 : (q < -32768 ? -32768 : q);
      stg_cohere_u16(wP + (size_t)eb * U_DIM + eu, (unsigned)q);

      const int tp = (t < T_LEN - 1) ? t + 1 : t;
      xq0 = ldg_sshort(xp + ((size_t)tp * B_SZ + eb) * G3 + eu);
      xq1 = ldg_sshort(xp + ((size_t)tp * B_SZ + eb) * G3 + 1024 + eu);
      xq2 = ldg_sshort(xp + ((size_t)tp * B_SZ + eb) * G3 + 2048 + eu);
      xtok = ldg_s32(x + eb * T_LEN + tp);
      WAITV(4);
    }

    __syncthreads();   // (2) epi stores drained; whole WG done with step t
    if (tid == 0)
      stg_cohere_u32(gflags + uj * 16, (unsigned)(t + 1));  // own line, no RMW
    __builtin_amdgcn_sched_barrier(0);
  }

  // final state = hp (exact register carry)
  if (epi)
    out[(size_t)B_SZ * T_LEN * U_DIM + (size_t)eb * U_DIM + eu] = hp;
}

// ---------------- launch
extern "C" void kernel_launch(void* const* d_in, const int* in_sizes, int n_in,
                              void* d_out, int out_size, void* d_ws, size_t ws_size,
                              hipStream_t stream) {
  const int*   x      = (const int*)  d_in[0];
  const float* hidden = (const float*)d_in[1];
  const float* emb    = (const float*)d_in[2];
  const float* Wx     = (const float*)d_in[3];
  const float* Wh     = (const float*)d_in[4];
  const float* b_i    = (const float*)d_in[5];
  const float* b_r    = (const float*)d_in[6];
  float* out = (float*)d_out;

  const size_t XP_B = (size_t)T_LEN * B_SZ * G3 * 2;   // 201,326,592 (int16)
  const size_t NEED = XP_B + 4 * (size_t)BU + 16384;   // + h16 x2 + flags
  if (ws_size < NEED) return;

  short*    xp    = (short*)d_ws;
  short*    h16   = (short*)((char*)d_ws + XP_B);      // [2][BU] int16
  unsigned* flags = (unsigned*)(h16 + 2 * (size_t)BU); // [4][64][16] u32

  init_h<<<BU / 256, 256, 0, stream>>>(hidden, h16, flags);
  gemm_xp<<<(32768 / 128) * (G3 / 128), 256, 0, stream>>>(emb, Wx, x, b_i, xp);
  gru_scan<<<NWG, 512, 0, stream>>>(hidden, Wh, b_r, xp, x, h16, flags, out);
}

// Round 10
// 2634.003 us; speedup vs baseline: 1.6270x; 1.1047x over previous
//
#include <hip/hip_runtime.h>
#include <stdint.h>

// GRU encoder: B=64 T=512 U=E=1024 V=32000, gates z|r|h, reset_after=True.
// Round-16 structure:
//   Phase 0: init_h  — quantize hidden -> int16 h-plane, zero 4096 flag words.
//   Phase 1: gemm_xp — 1-TERM plain-bf16 gather GEMM (was 3-term split).
//     Rationale: measured absmax 2.441e-4 == bf16 OUTPUT floor (pipeline was
//     exact) with 5.8x margin to threshold. 1-term adds ~3.2e-5 rms to gate
//     pre-activations (vs int16 quant 7.6e-6 already there) -> <=~1e-4 on
//     output. Cuts gemm MFMAs 3x + halves staging VALU/LDS.
//   Phase 2: gru_scan — r15 data path + straggler-aware barrier shortcut:
//     (a) wave-7 pre-poll (2 bounded iters, no sleep, capped < epi window)
//         posts LDS `ready`; wave 0 skips main poll when set — saves ~700cy
//         on the straggler WG that sets the group pace.
//     (b) poll s_sleep(2)->(1); (c) epi stores h16-first + WAITV(5) so the
//         flag gates only on the h-store ack. All WAITV counts re-verified.
//     History: r11 payload-halving neutral; r14 dataflow regressed (poll
//     mechanics); r15 parallel-flag arrival small win. Chain now ~fully
//     probed; this is the last latency term (detect) + the gemm-side win.
// ws: xp 201.33MB | h16 2x128KB | flags 16KB = 201.60MB.

#define B_SZ   64
#define T_LEN  512
#define U_DIM  1024
#define E_DIM  1024
#define G3     3072
#define BU     (B_SZ * U_DIM)
#define XP_SCALE 131072.0f
#define XP_INV   (1.0f / 131072.0f)
#define H_SCALE  32768.0f
#define H_INV    (1.0f / 32768.0f)
#define LDT    40   // gemm LDS row stride (ushorts): 80B, 16B-aligned
#define NWG    256

typedef unsigned short ushort_t;
typedef __attribute__((ext_vector_type(8))) short bf16x8;
typedef __attribute__((ext_vector_type(4))) float f32x4;

__device__ __forceinline__ ushort_t f2bf(float f) {
  unsigned u = __builtin_bit_cast(unsigned, f);
  u += 0x7fffu + ((u >> 16) & 1u);          // RNE
  return (ushort_t)(u >> 16);
}
__device__ __forceinline__ float bf2f(ushort_t h) {
  return __builtin_bit_cast(float, (unsigned)h << 16);
}

// ---- coherent (MALL-point) memory ops: bypass L1+L2 via sc0 sc1 ----
__device__ __forceinline__ bf16x8 ldg_cohere_b128(const void* p) {
  bf16x8 r;
  asm volatile("global_load_dwordx4 %0, %1, off sc0 sc1"
               : "=v"(r) : "v"(p) : "memory");
  return r;
}
__device__ __forceinline__ void stg_cohere_u16(short* p, unsigned v) {
  asm volatile("global_store_short %0, %1, off sc0 sc1"
               :: "v"(p), "v"(v) : "memory");
}
__device__ __forceinline__ void stg_cohere_u32(unsigned* p, unsigned v) {
  asm volatile("global_store_dword %0, %1, off sc0 sc1"
               :: "v"(p), "v"(v) : "memory");
}
__device__ __forceinline__ unsigned ldg_cohere_u32(const unsigned* p) {
  unsigned r;
  asm volatile("global_load_dword %0, %1, off sc0 sc1\n\ts_waitcnt vmcnt(0)"
               : "=v"(r) : "v"(p) : "memory");
  return r;
}
// ---- ordinary cached ops, but as ordered volatile asm (vmcnt counting) ----
__device__ __forceinline__ int ldg_sshort(const short* p) {
  int r;
  asm volatile("global_load_sshort %0, %1, off"
               : "=v"(r) : "v"(p) : "memory");
  return r;
}
__device__ __forceinline__ int ldg_s32(const int* p) {
  int r;
  asm volatile("global_load_dword %0, %1, off"
               : "=v"(r) : "v"(p) : "memory");
  return r;
}
__device__ __forceinline__ void stg_u32(float* p, float v) {
  asm volatile("global_store_dword %0, %1, off"
               :: "v"(p), "v"(v) : "memory");
}
#define WAITV(n) do { asm volatile("s_waitcnt vmcnt(" #n ")" ::: "memory"); \
                      __builtin_amdgcn_sched_barrier(0); } while (0)

// ---------------- Phase 1: gathered GEMM, 128x128 tile, BK=32, 4 waves,
// 1-term plain bf16 (hi-only staging), 20.5KB static LDS.
__global__ __launch_bounds__(256) void gemm_xp(
    const float* __restrict__ emb,    // [V][1024] f32 (gathered rows)
    const float* __restrict__ Wx,     // [1024][3072] f32
    const int* __restrict__ x,        // [B*T] (m = b*T+t)
    const float* __restrict__ b_i,    // [3072]
    short* __restrict__ xp)           // [T][B][3072] int16 (x 2^17)
{
  __shared__ ushort_t aH[128 * LDT];
  __shared__ ushort_t bH[128 * LDT];
  const int tid = threadIdx.x, lane = tid & 63, w = tid >> 6;
  const int bx = blockIdx.x;
  const int nIdx = bx % 24, mIdx = bx / 24;
  const int m0 = mIdx * 128, n0 = nIdx * 128;

  const int aRow0 = tid >> 2, aRow1 = (tid + 256) >> 2, aKoct = tid & 3;
  const size_t aBase0 = (size_t)x[m0 + aRow0] * E_DIM + (size_t)aKoct * 8;
  const size_t aBase1 = (size_t)x[m0 + aRow1] * E_DIM + (size_t)aKoct * 8;
  const int bN = tid & 127, bKoct0 = tid >> 7;

  const int wr = (w >> 1) * 64, wc = (w & 1) * 64;
  f32x4 acc[4][4];
#pragma unroll
  for (int i = 0; i < 4; i++)
#pragma unroll
    for (int j = 0; j < 4; j++) acc[i][j] = (f32x4){0.f, 0.f, 0.f, 0.f};

  for (int k0 = 0; k0 < E_DIM; k0 += 32) {
    __syncthreads();
#pragma unroll
    for (int pp = 0; pp < 2; ++pp) {
      const float* src = emb + (pp ? aBase1 : aBase0) + k0;
      int row = pp ? aRow1 : aRow0;
      float4 v0 = *(const float4*)(src);
      float4 v1 = *(const float4*)(src + 4);
      float vv[8] = {v0.x, v0.y, v0.z, v0.w, v1.x, v1.y, v1.z, v1.w};
      bf16x8 oh;
#pragma unroll
      for (int j = 0; j < 8; ++j) oh[j] = (short)f2bf(vv[j]);
      *(bf16x8*)&aH[row * LDT + aKoct * 8] = oh;
    }
#pragma unroll
    for (int kk = 0; kk < 2; ++kk) {
      int koct = bKoct0 + 2 * kk;
      float vv[8];
#pragma unroll
      for (int e = 0; e < 8; ++e)
        vv[e] = Wx[(size_t)(k0 + koct * 8 + e) * G3 + n0 + bN];
      bf16x8 oh;
#pragma unroll
      for (int j = 0; j < 8; ++j) oh[j] = (short)f2bf(vv[j]);
      *(bf16x8*)&bH[bN * LDT + koct * 8] = oh;
    }
    __syncthreads();
    bf16x8 afH[4], bfH[4];
#pragma unroll
    for (int mi = 0; mi < 4; mi++) {
      int off = (wr + mi * 16 + (lane & 15)) * LDT + (lane >> 4) * 8;
      afH[mi] = *(const bf16x8*)&aH[off];
    }
#pragma unroll
    for (int ni = 0; ni < 4; ni++) {
      int off = (wc + ni * 16 + (lane & 15)) * LDT + (lane >> 4) * 8;
      bfH[ni] = *(const bf16x8*)&bH[off];
    }
#pragma unroll
    for (int mi = 0; mi < 4; mi++)
#pragma unroll
      for (int ni = 0; ni < 4; ni++)
        acc[mi][ni] = __builtin_amdgcn_mfma_f32_16x16x32_bf16(afH[mi], bfH[ni], acc[mi][ni], 0, 0, 0);
  }
#pragma unroll
  for (int ni = 0; ni < 4; ni++) {
    int col = n0 + wc + ni * 16 + (lane & 15);
    float bias = b_i[col];
#pragma unroll
    for (int mi = 0; mi < 4; mi++) {
      int rbase = m0 + wr + mi * 16 + (lane >> 4) * 4;
#pragma unroll
      for (int i = 0; i < 4; i++) {
        int m = rbase + i;
        int b = m >> 9, t = m & 511;
        float v = acc[mi][ni][i] + bias;
        int q = __float2int_rn(v * XP_SCALE);
        q = q > 32767 ? 32767 : (q < -32768 ? -32768 : q);
        xp[(size_t)(t * 64 + b) * G3 + col] = (short)q;
      }
    }
  }
}

// ---------------- Phase 0: quantize hidden -> int16 h-plane (buffer 0),
// zero the 4096 flag words (4 groups x 64 flags x 16-dword stride).
__global__ __launch_bounds__(256) void init_h(
    const float* __restrict__ hidden,
    short* __restrict__ h16,
    unsigned* __restrict__ flags)
{
  const int i = blockIdx.x * 256 + threadIdx.x;
  if (blockIdx.x < 16) flags[blockIdx.x * 256 + threadIdx.x] = 0u;
  if (i < BU) {
    int q = __float2int_rn(hidden[i] * H_SCALE);
    q = q > 32767 ? 32767 : (q < -32768 ? -32768 : q);
    h16[i] = (short)q;
  }
}

// ---------------- Phase 2: persistent GRU scan, parallel-flag barrier +
// wave-7 pre-poll shortcut. WG(bx): uj = bx&63 (u-tile of 16), bi = bx>>6
// (batch-group of 16 rows). Wave w (0..7) owns K-segment [128w,128w+128).
// Verified MFMA layouts: A row=lane&15 k=(lane>>4)*8+j; B col=lane&15 same
// k; C row=(lane>>4)*4+i col=lane&15. h exchanged as int16 @2^15 (one
// plane, double-buffered); unpacked to EXACT split-bf16 in VALU.
// Barrier: arrival = tid0 plain sc0sc1 store to own 64B-padded flag (after
// sync(1) reads-consumed + WAITV h16-drained + sync(2)); detection = wave-0
// 64-lane flag read (skipped when wave-7's bounded pre-poll already saw all
// flags >= t during the epi window), s_sleep(1), syncthreads release.
__global__ __launch_bounds__(512) void gru_scan(
    const float* __restrict__ hidden,  // [64][1024] f32 (hp init)
    const float* __restrict__ Wh,      // [1024][3072] f32
    const float* __restrict__ b_r,     // [3072]
    const short* __restrict__ xp,      // [T][64][3072] int16
    const int* __restrict__ x,         // [64][512]
    short* __restrict__ h16,           // [2][64][1024] int16 @2^15
    unsigned* __restrict__ flags,      // [4][64][16] u32 (flag per 64B line)
    float* __restrict__ out)           // [64][512][1024] f32 + [64][1024] state
{
  __shared__ float part[8][3][64][4];   // [kseg][gate][lane][elem] 24KB
  __shared__ unsigned ready;            // wave-7 pre-poll verdict
  const int tid  = threadIdx.x;
  const int lane = tid & 63;
  const int w    = tid >> 6;            // wave id = K-segment
  const int bx   = (int)blockIdx.x;
  const int uj   = bx & 63, bi = bx >> 6;
  const int u0   = uj * 16, b0 = bi * 16;
  const int c16  = lane & 15;           // fragment row/col-within-tile
  const int kg   = lane >> 4;           // k-group (x8)
  unsigned* gflags = flags + bi * 1024;         // this group's 64 flag lines
  const unsigned* pollp = gflags + lane * 16;   // poller lane -> one flag

  // ---- Wh fragments resident in registers (built once, cached loads) ----
  bf16x8 BH[4][3], BL[4][3];
#pragma unroll
  for (int ks = 0; ks < 4; ++ks)
#pragma unroll
    for (int g = 0; g < 3; ++g) {
      bf16x8 bh, bl;
#pragma unroll
      for (int j = 0; j < 8; ++j) {
        int k = w * 128 + ks * 32 + kg * 8 + j;
        float v = Wh[(size_t)k * G3 + g * 1024 + u0 + c16];
        ushort_t hi = f2bf(v);
        bh[j] = (short)hi;
        bl[j] = (short)f2bf(v - bf2f(hi));
      }
      BH[ks][g] = bh;
      BL[ks][g] = bl;
    }

  // ---- epilogue ownership: waves 0-3 (tid<256): one (b,u) per thread ----
  const bool epi = (tid < 256);
  const int ebl = (tid >> 4) & 15, eul = tid & 15;
  const int eb = b0 + ebl, eu = u0 + eul;
  float brz = 0.f, brr = 0.f, brh = 0.f, hp = 0.f;
  if (epi) {
    brz = b_r[eu]; brr = b_r[1024 + eu]; brh = b_r[2048 + eu];
    hp  = hidden[(size_t)eb * U_DIM + eu];
  }

  // drain everything before entering the counted-vmcnt regime
  asm volatile("s_waitcnt vmcnt(0) lgkmcnt(0)" ::: "memory");

  // prologue: prefetch xq for t=0 (epi waves carry 4 extra in-flight loads;
  // every WAITV below is FIFO oldest-first and correct for both wave classes;
  // wave-0/7 poll vmcnt(0) merely retires their older ops early).
  int xq0 = 0, xq1 = 0, xq2 = 0, xtok = 0;
  if (epi) {
    xq0 = ldg_sshort(xp + (size_t)eb * G3 + eu);
    xq1 = ldg_sshort(xp + (size_t)eb * G3 + 1024 + eu);
    xq2 = ldg_sshort(xp + (size_t)eb * G3 + 2048 + eu);
    xtok = ldg_s32(x + eb * T_LEN + 0);
  }

  unsigned spins = 0;            // global spin budget: deadlock bails visibly
  for (int t = 0; t < T_LEN; ++t) {
    const short* __restrict__ rP = h16 + (size_t)(t & 1) * BU;
    short* __restrict__ wP       = h16 + (size_t)((t + 1) & 1) * BU;

    // ---- barrier wait: all 64 group flags >= t; skipped if wave-7's
    // pre-poll already confirmed during last step's epi window ----
    if (t > 0) {
      if (w == 0) {
        if (ready == 0u) {
          const unsigned tgt = (unsigned)t;
          while (spins < (1u << 22)) {
            unsigned f = ldg_cohere_u32(pollp);   // 64 lanes -> 64 flags
            if (__ballot(f >= tgt) == ~0ull) break;
            __builtin_amdgcn_s_sleep(1);
            ++spins;
          }
        }
      }
      __syncthreads();   // release: h(t) fully MALL-visible
    }

    // A rows = this group's 16 h-rows; row c16, k-base w*128 + kg*8
    const short* pP = rP + (size_t)(b0 + c16) * U_DIM + w * 128 + kg * 8;

    f32x4 acc[3];
#pragma unroll
    for (int g = 0; g < 3; ++g) acc[g] = (f32x4){0.f, 0.f, 0.f, 0.f};

    // issue all 4 packed A-loads upfront; FIFO waits (epi waves carry 5
    // older ops [out,xq x4] in steady state; oldest retire first -> counts
    // valid for every wave class):
    //   WAITV(3)->P0 done, WAITV(2)->P1, WAITV(1)->P2, WAITV(0)->P3.
    bf16x8 P0, P1, P2, P3;
    P0 = ldg_cohere_b128(pP + 0 * 32);
    P1 = ldg_cohere_b128(pP + 1 * 32);
    P2 = ldg_cohere_b128(pP + 2 * 32);
    P3 = ldg_cohere_b128(pP + 3 * 32);

    // unpack int16 -> EXACT split bf16 (hi 8 mant bits + lo rest), then MFMA
#define UNPCK(P_, AH_, AL_) \
    { \
      _Pragma("unroll") \
      for (int j = 0; j < 8; ++j) { \
        float v = (float)(short)P_[j] * H_INV; \
        ushort_t hi = f2bf(v); \
        AH_[j] = (short)hi; \
        AL_[j] = (short)f2bf(v - bf2f(hi)); \
      } \
    }
#define COMP(AH_, AL_, ks_) \
    _Pragma("unroll") \
    for (int g = 0; g < 3; ++g) { \
      acc[g] = __builtin_amdgcn_mfma_f32_16x16x32_bf16(AH_, BH[ks_][g], acc[g], 0, 0, 0); \
      acc[g] = __builtin_amdgcn_mfma_f32_16x16x32_bf16(AH_, BL[ks_][g], acc[g], 0, 0, 0); \
      acc[g] = __builtin_amdgcn_mfma_f32_16x16x32_bf16(AL_, BH[ks_][g], acc[g], 0, 0, 0); \
    }
    bf16x8 AH, AL;
    WAITV(3);
    UNPCK(P0, AH, AL)
    COMP(AH, AL, 0)
    WAITV(2);
    UNPCK(P1, AH, AL)
    COMP(AH, AL, 1)
    WAITV(1);
    UNPCK(P2, AH, AL)
    COMP(AH, AL, 2)
    WAITV(0);
    UNPCK(P3, AH, AL)
    COMP(AH, AL, 3)
#undef UNPCK
#undef COMP

    // ---- K-segment partials -> LDS, lane-major: contiguous b128 writes ----
#pragma unroll
    for (int g = 0; g < 3; ++g)
      *(f32x4*)&part[w][g][lane][0] = acc[g];

    __syncthreads();   // (1) parts visible; ALL waves' A-reads consumed

    if (epi) {
      // C elem: row ebl col eul -> producer lane (ebl>>2)*16+eul, elem ebl&3
      const int pl = (ebl >> 2) * 16 + eul, pe = ebl & 3;
      float sz = 0.f, sr = 0.f, sh = 0.f;
#pragma unroll
      for (int s = 0; s < 8; ++s) {
        sz += part[s][0][pl][pe];
        sr += part[s][1][pl][pe];
        sh += part[s][2][pl][pe];
      }

      // ---- fused gate epilogue (xq values prefetched last iteration) ----
      const float hz = sz + brz, hr = sr + brr, hhv = sh + brh;
      const float xz = (float)xq0 * XP_INV;
      const float xr = (float)xq1 * XP_INV;
      const float xh = (float)xq2 * XP_INV;
      const float z = 1.f / (1.f + __expf(-(xz + hz)));
      const float r = 1.f / (1.f + __expf(-(xr + hr)));
      const float ca = xh + r * hhv;
      const float cand = 1.f - 2.f / (__expf(2.f * ca) + 1.f);   // tanh
      float hn = z * hp + (1.f - z) * cand;
      hn = (xtok != 0) ? hn : hp;
      hp = hn;

      // ordered stores: h16 FIRST (the flag gate), then out, then 4 xq
      // prefetches; WAITV(5) drains exactly [h16] (oldest) -> h visible at
      // MALL; out + xq still flying (out is stream-ordered, host-only).
      int q = __float2int_rn(hn * H_SCALE);
      q = q > 32767 ? 32767 : (q < -32768 ? -32768 : q);
      stg_cohere_u16(wP + (size_t)eb * U_DIM + eu, (unsigned)q);
      stg_u32(&out[((size_t)eb * T_LEN + t) * U_DIM + eu], hn);

      const int tp = (t < T_LEN - 1) ? t + 1 : t;
      xq0 = ldg_sshort(xp + ((size_t)tp * B_SZ + eb) * G3 + eu);
      xq1 = ldg_sshort(xp + ((size_t)tp * B_SZ + eb) * G3 + 1024 + eu);
      xq2 = ldg_sshort(xp + ((size_t)tp * B_SZ + eb) * G3 + 2048 + eu);
      xtok = ldg_s32(x + eb * T_LEN + tp);
      WAITV(5);
    } else if (w == 7) {
      // ---- bounded pre-poll for step t+1 during the epi window (costs at
      // most ~2 MALL RTs, < epi epilogue length -> never delays our flag).
      const unsigned tgt2 = (unsigned)(t + 1);
      unsigned ok = 0;
#pragma unroll
      for (int it = 0; it < 2; ++it) {
        if (!ok) {
          unsigned f = ldg_cohere_u32(pollp);
          if (__ballot(f >= tgt2) == ~0ull) ok = 1u;
        }
      }
      if (lane == 0) ready = ok;
    }

    __syncthreads();   // (2) epi h16 drained; whole WG done with step t
    if (tid == 0)
      stg_cohere_u32(gflags + uj * 16, (unsigned)(t + 1));  // own line, no RMW
    __builtin_amdgcn_sched_barrier(0);
  }

  // final state = hp (exact register carry)
  if (epi)
    out[(size_t)B_SZ * T_LEN * U_DIM + (size_t)eb * U_DIM + eu] = hp;
}

// ---------------- launch
extern "C" void kernel_launch(void* const* d_in, const int* in_sizes, int n_in,
                              void* d_out, int out_size, void* d_ws, size_t ws_size,
                              hipStream_t stream) {
  const int*   x      = (const int*)  d_in[0];
  const float* hidden = (const float*)d_in[1];
  const float* emb    = (const float*)d_in[2];
  const float* Wx     = (const float*)d_in[3];
  const float* Wh     = (const float*)d_in[4];
  const float* b_i    = (const float*)d_in[5];
  const float* b_r    = (const float*)d_in[6];
  float* out = (float*)d_out;

  const size_t XP_B = (size_t)T_LEN * B_SZ * G3 * 2;   // 201,326,592 (int16)
  const size_t NEED = XP_B + 4 * (size_t)BU + 16384;   // + h16 x2 + flags
  if (ws_size < NEED) return;

  short*    xp    = (short*)d_ws;
  short*    h16   = (short*)((char*)d_ws + XP_B);      // [2][BU] int16
  unsigned* flags = (unsigned*)(h16 + 2 * (size_t)BU); // [4][64][16] u32

  init_h<<<BU / 256, 256, 0, stream>>>(hidden, h16, flags);
  gemm_xp<<<(32768 / 128) * (G3 / 128), 256, 0, stream>>>(emb, Wx, x, b_i, xp);
  gru_scan<<<NWG, 512, 0, stream>>>(hidden, Wh, b_r, xp, x, h16, flags, out);
}